// Round 12
// baseline (134.763 us; speedup 1.0000x reference)
//
#include <hip/hip_runtime.h>
#include <stdint.h>

// MultiHeadSelfAttention: x[2,2048,1024] fp32, w_qkv[1024,3072], w_proj[1024,1024], b_proj[1024]
// prep(cvt+trw) -> GEMM1(qkv, 64x128 tile, 6 blk/CU, gload_lds, XCD strips, V transposed) ->
// flash6 (swapped-operand, chunked LDS, fixed-max softmax, kv-split x2, MFMA-lsum) ->
// GEMM2(+bias, 64x64 tile, 4 blk/CU)

typedef unsigned short u16;
typedef uint32_t u32;
typedef __bf16 bf16x8 __attribute__((ext_vector_type(8)));
typedef unsigned short u16x8 __attribute__((ext_vector_type(8)));
typedef float f32x4 __attribute__((ext_vector_type(4)));
typedef float f32x16 __attribute__((ext_vector_type(16)));
typedef uint32_t u32x2v __attribute__((ext_vector_type(2)));
typedef uint32_t u32x4v __attribute__((ext_vector_type(4)));

#define DEV static __device__ __forceinline__

DEV u16 f2bf(float f) {
    uint32_t u = __float_as_uint(f);
    u += 0x7fffu + ((u >> 16) & 1u);
    return (u16)(u >> 16);
}

DEV u32 cvtpk(float lo, float hi_) {
    u32 r;
    asm("v_cvt_pk_bf16_f32 %0, %1, %2" : "=v"(r) : "v"(lo), "v"(hi_));
    return r;
}
DEV void plswap(u32& x, u32& y) {
    asm("v_permlane32_swap_b32 %0, %1" : "+v"(x), "+v"(y));
}
DEV float exp2f_fast(float x) {
    float r;
    asm("v_exp_f32 %0, %1" : "=v"(r) : "v"(x));
    return r;
}

DEV void gload_lds16(const void* g, void* l) {
    __builtin_amdgcn_global_load_lds(
        (const __attribute__((address_space(1))) uint32_t*)g,
        (__attribute__((address_space(3))) uint32_t*)l, 16, 0, 0);
}

#define WAIT_VM(N) asm volatile("s_waitcnt vmcnt(" #N ")" ::: "memory")
#define RAW_BAR() __builtin_amdgcn_s_barrier()
#define SCHED_PIN() __builtin_amdgcn_sched_barrier(0)

// GEMM LDS read: [row][64] bf16 rows (128B), XOR swizzle byte ^= (row&7)<<4.
DEV bf16x8 swz_load16(const u16* base, int row, int kbyte) {
    int off = (row * 128 + kbyte) ^ ((row & 7) << 4);
    return *reinterpret_cast<const bf16x8*>(reinterpret_cast<const char*>(base) + off);
}

// ---------------- prep: cvt_x + transpose both weights (fused, one launch) ----------------
__global__ __launch_bounds__(256) void prep_kernel(
    const float* __restrict__ x, u16* __restrict__ xb,
    const float* __restrict__ wq, u16* __restrict__ wqt,
    const float* __restrict__ wp, u16* __restrict__ wpt) {
    __shared__ float T[32][33];
    int b = blockIdx.x, tid = threadIdx.x;
    if (b < 2048) {
        int t = b * 256 + tid;
        const float4* p = reinterpret_cast<const float4*>(x) + (size_t)t * 2;
        float4 a = p[0], c = p[1];
        u16x8 o;
        o[0] = f2bf(a.x); o[1] = f2bf(a.y); o[2] = f2bf(a.z); o[3] = f2bf(a.w);
        o[4] = f2bf(c.x); o[5] = f2bf(c.y); o[6] = f2bf(c.z); o[7] = f2bf(c.w);
        reinterpret_cast<u16x8*>(xb)[t] = o;
        return;
    }
    const float* in;
    u16* out;
    int bx, by, R = 1024, Cc;
    if (b < 5120) {
        int idx = b - 2048;
        bx = idx % 96; by = idx / 96; Cc = 3072; in = wq; out = wqt;
    } else {
        int idx = b - 5120;
        bx = idx % 32; by = idx / 32; Cc = 1024; in = wp; out = wpt;
    }
    int tx = tid & 31, ty = tid >> 5;
    int xcol = bx * 32 + tx;
    int y0 = by * 32;
#pragma unroll
    for (int i = 0; i < 4; i++) {
        int y = y0 + ty + i * 8;
        T[ty + i * 8][tx] = in[(size_t)y * Cc + xcol];
    }
    __syncthreads();
    int xo = y0 + tx;
    int yo0 = bx * 32;
#pragma unroll
    for (int i = 0; i < 4; i++) {
        int yo = yo0 + ty + i * 8;
        out[(size_t)yo * R + xo] = f2bf(T[tx][ty + i * 8]);
    }
}

// ---------------- GEMM1: xb[4096,1024] x wqt[3072,1024]^T, 64x128 tile, 4 waves ----------------
// Wave w: rows wr*32 (wr=w>>1), cols wc*64 (wc=w&1); acc[2][4]. Grid 1536 = 8 XCD x 8 bm x 24 bn.
__global__ __launch_bounds__(256, 6) void gemm1_kernel(
    const u16* __restrict__ A, const u16* __restrict__ Bt,
    u16* __restrict__ o_q, u16* __restrict__ o_k, u16* __restrict__ o_vt) {
    __shared__ __align__(16) u16 Al[4096];    // 64 x 64
    __shared__ __align__(16) u16 Bl[8192];    // 128 x 64
    int tid = threadIdx.x;
    int p = blockIdx.x;
    int xcd = p & 7, q = p >> 3;
    int bm = xcd * 8 + q / 24, bn = q % 24;
    int lane = tid & 63, w = tid >> 6;
    int wr = w >> 1, wc = w & 1;
    int l15 = lane & 15, lhi = lane >> 4;

    f32x4 acc[2][4];
#pragma unroll
    for (int i = 0; i < 2; i++)
#pragma unroll
        for (int j = 0; j < 4; j++) acc[i][j] = (f32x4){0.f, 0.f, 0.f, 0.f};

    for (int kt = 0; kt < 16; ++kt) {
#pragma unroll
        for (int i = 0; i < 2; i++) {  // A: 8 KB
            int lin = tid * 16 + i * 4096;
            int row = lin >> 7;
            int src = (lin & 127) ^ ((row & 7) << 4);
            gload_lds16((const char*)A + (size_t)(bm * 64 + row) * 2048 + (size_t)kt * 128 + src,
                        (char*)Al + lin);
        }
#pragma unroll
        for (int i = 0; i < 4; i++) {  // B: 16 KB
            int lin = tid * 16 + i * 4096;
            int row = lin >> 7;
            int src = (lin & 127) ^ ((row & 7) << 4);
            gload_lds16((const char*)Bt + (size_t)(bn * 128 + row) * 2048 + (size_t)kt * 128 + src,
                        (char*)Bl + lin);
        }
        __syncthreads();
#pragma unroll
        for (int ks = 0; ks < 2; ++ks) {
            bf16x8 af[2], bfr[4];
#pragma unroll
            for (int mi = 0; mi < 2; ++mi) af[mi] = swz_load16(Al, wr * 32 + mi * 16 + l15, ks * 64 + lhi * 16);
#pragma unroll
            for (int ni = 0; ni < 4; ++ni) bfr[ni] = swz_load16(Bl, wc * 64 + ni * 16 + l15, ks * 64 + lhi * 16);
            __builtin_amdgcn_s_setprio(1);
#pragma unroll
            for (int mi = 0; mi < 2; ++mi)
#pragma unroll
                for (int ni = 0; ni < 4; ++ni)
                    acc[mi][ni] = __builtin_amdgcn_mfma_f32_16x16x32_bf16(af[mi], bfr[ni], acc[mi][ni], 0, 0, 0);
            __builtin_amdgcn_s_setprio(0);
        }
        __syncthreads();
    }

    int row0 = bm * 64 + wr * 32, col0 = bn * 128 + wc * 64;
#pragma unroll
    for (int mi = 0; mi < 2; mi++)
#pragma unroll
        for (int ni = 0; ni < 4; ni++) {
            int col = col0 + ni * 16 + l15;
            int sel = col >> 10, cc = col & 1023;
            int h = cc >> 6, d = cc & 63;
            int r0 = row0 + mi * 16 + lhi * 4;
            int b = r0 >> 11, n0 = r0 & 2047;
            if (sel == 2) {
                u32x2v pk2 = {cvtpk(acc[mi][ni][0], acc[mi][ni][1]),
                              cvtpk(acc[mi][ni][2], acc[mi][ni][3])};
                *reinterpret_cast<u32x2v*>(o_vt + ((size_t)(b * 16 + h) * 64 + d) * 2048 + n0) = pk2;
            } else {
                size_t base = (((size_t)(b * 16 + h)) * 2048 + n0) * 64 + d;
#pragma unroll
                for (int j = 0; j < 4; j++) {
                    float v = acc[mi][ni][j];
                    if (sel == 0) o_q[base + (size_t)j * 64] = f2bf(v * 0.18033688f);  // 0.125*log2e
                    else o_k[base + (size_t)j * 64] = f2bf(v);
                }
            }
        }
}

// ---------------- GEMM2: attn[4096,1024] x wpt[1024,1024]^T + bias, 64x64 tile, 4 waves ----------------
// Wave w: rows wr*32, cols wc*32; acc[2][2]. Grid 1024 = 8 XCD x 8 bm x 16 bn.
__global__ __launch_bounds__(256, 4) void gemm2_kernel(
    const u16* __restrict__ A, const u16* __restrict__ Bt,
    float* __restrict__ o_f, const float* __restrict__ bias) {
    __shared__ __align__(16) u16 Al[4096];
    __shared__ __align__(16) u16 Bl[4096];
    int tid = threadIdx.x;
    int p = blockIdx.x;
    int xcd = p & 7, q = p >> 3;
    int bm = xcd * 8 + q / 16, bn = q % 16;
    int lane = tid & 63, w = tid >> 6;
    int wr = w >> 1, wc = w & 1;
    int l15 = lane & 15, lhi = lane >> 4;

    f32x4 acc[2][2];
#pragma unroll
    for (int i = 0; i < 2; i++)
#pragma unroll
        for (int j = 0; j < 2; j++) acc[i][j] = (f32x4){0.f, 0.f, 0.f, 0.f};

    for (int kt = 0; kt < 16; ++kt) {
#pragma unroll
        for (int i = 0; i < 2; i++) {
            int lin = tid * 16 + i * 4096;
            int row = lin >> 7;
            int src = (lin & 127) ^ ((row & 7) << 4);
            gload_lds16((const char*)A + (size_t)(bm * 64 + row) * 2048 + (size_t)kt * 128 + src,
                        (char*)Al + lin);
            gload_lds16((const char*)Bt + (size_t)(bn * 64 + row) * 2048 + (size_t)kt * 128 + src,
                        (char*)Bl + lin);
        }
        __syncthreads();
#pragma unroll
        for (int ks = 0; ks < 2; ++ks) {
            bf16x8 af[2], bfr[2];
#pragma unroll
            for (int mi = 0; mi < 2; ++mi) af[mi] = swz_load16(Al, wr * 32 + mi * 16 + l15, ks * 64 + lhi * 16);
#pragma unroll
            for (int ni = 0; ni < 2; ++ni) bfr[ni] = swz_load16(Bl, wc * 32 + ni * 16 + l15, ks * 64 + lhi * 16);
            __builtin_amdgcn_s_setprio(1);
#pragma unroll
            for (int mi = 0; mi < 2; ++mi)
#pragma unroll
                for (int ni = 0; ni < 2; ++ni)
                    acc[mi][ni] = __builtin_amdgcn_mfma_f32_16x16x32_bf16(af[mi], bfr[ni], acc[mi][ni], 0, 0, 0);
            __builtin_amdgcn_s_setprio(0);
        }
        __syncthreads();
    }

    int row0 = bm * 64 + wr * 32, col0 = bn * 64 + wc * 32;
#pragma unroll
    for (int mi = 0; mi < 2; mi++)
#pragma unroll
        for (int ni = 0; ni < 2; ni++) {
            int col = col0 + ni * 16 + l15;
            float bb = bias[col];
#pragma unroll
            for (int j = 0; j < 4; j++) {
                int r = row0 + mi * 16 + lhi * 4 + j;
                o_f[(size_t)r * 1024 + col] = acc[mi][ni][j] + bb;
            }
        }
}

// ---------------- flash6: fixed-max softmax + kv-split x2, zero-C MFMA + MFMA-lsum ----------------
__global__ __launch_bounds__(512, 4) void flash6_kernel(
    const u16* __restrict__ qg, const u16* __restrict__ kg, const u16* __restrict__ vtg,
    u16* __restrict__ o) {
    __shared__ __align__(16) char smem[65536];

    int tid = threadIdx.x, lane = tid & 63, w = tid >> 6;
    int wg = w & 3, g = w >> 2;
    int l31 = lane & 31, hi = lane >> 5;
    int p = blockIdx.y * 16 + blockIdx.x;
    int bh = p & 31, qt = p >> 5;  // p%8 = XCD: each XCD sees 4 distinct bh -> K/V L2-local
    int q0 = qt * 128 + wg * 32;

#define KL(gg, bb) (smem + ((gg) * 2 + (bb)) * 8192)
#define VL(gg, bb) (smem + 32768 + ((gg) * 2 + (bb)) * 8192)

    const u16* qp = qg + ((size_t)bh * 2048 + q0 + l31) * 64 + hi * 8;
    bf16x8 qf[4];
#pragma unroll
    for (int ds = 0; ds < 4; ds++) qf[ds] = *reinterpret_cast<const bf16x8*>(qp + ds * 16);

    const char* kbg = (const char*)(kg + (size_t)bh * 2048 * 64) + (size_t)g * 16 * 8192;
    const char* vbg = (const char*)(vtg + (size_t)bh * 64 * 2048) + (size_t)g * 2048;

    int srow = lane >> 1, sinner = (lane & 1) * 16;
    int fbase = l31 * 32 + hi * 16;

#define STAGE(bb, tt)                                                                     \
    {                                                                                     \
        _Pragma("unroll") for (int i = 0; i < 2; i++) {                                   \
            gload_lds16(kbg + (size_t)(tt) * 8192 + (i * 32 + srow) * 128 + wg * 32 + sinner, \
                        KL(g, bb) + wg * 2048 + i * 1024 + lane * 16);                    \
            gload_lds16(vbg + (size_t)(i * 32 + srow) * 4096 + (size_t)(tt) * 128 + wg * 32 + sinner, \
                        VL(g, bb) + wg * 2048 + i * 1024 + lane * 16);                    \
        }                                                                                 \
    }

    f32x16 fzero;
#pragma unroll
    for (int r = 0; r < 16; r++) fzero[r] = 0.f;
    f32x16 accO[2], accL;
#pragma unroll
    for (int db = 0; db < 2; db++) accO[db] = fzero;
    accL = fzero;
    u16x8 ou;
#pragma unroll
    for (int j = 0; j < 8; j++) ou[j] = 0x3F80;  // bf16 1.0
    bf16x8 ones = __builtin_bit_cast(bf16x8, ou);

    STAGE(0, 0);

    for (int pp = 0; pp < 16; ++pp) {
        int c = pp & 1;
        if (pp < 15) {
            STAGE(c ^ 1, pp + 1);  // 4 loads stay in flight across the barrier
            WAIT_VM(4);            // wait only stage(pp)
        } else {
            WAIT_VM(0);
        }
        RAW_BAR();
        SCHED_PIN();

        // QK: S^T = K * Q^T
        bf16x8 ka[2][4];
#pragma unroll
        for (int kvb = 0; kvb < 2; kvb++)
#pragma unroll
            for (int ds = 0; ds < 4; ds++)
                ka[kvb][ds] = *reinterpret_cast<const bf16x8*>(KL(g, c) + ds * 2048 + kvb * 1024 + fbase);
        f32x16 s[2];
        __builtin_amdgcn_s_setprio(1);
#pragma unroll
        for (int kvb = 0; kvb < 2; kvb++) {
            s[kvb] = __builtin_amdgcn_mfma_f32_32x32x16_bf16(ka[kvb][0], qf[0], fzero, 0, 0, 0);
#pragma unroll
            for (int ds = 1; ds < 4; ds++)
                s[kvb] = __builtin_amdgcn_mfma_f32_32x32x16_bf16(ka[kvb][ds], qf[ds], s[kvb], 0, 0, 0);
        }
        __builtin_amdgcn_s_setprio(0);

        // fixed-max softmax: P = exp2(s)  (Q pre-scaled by 0.125*log2e)
#pragma unroll
        for (int kvb = 0; kvb < 2; kvb++)
#pragma unroll
            for (int r = 0; r < 16; r++) s[kvb][r] = exp2f_fast(s[kvb][r]);

        // P^T B-frags in-register
        bf16x8 pb[4];
#pragma unroll
        for (int kvb = 0; kvb < 2; kvb++) {
            u32 x0 = cvtpk(s[kvb][0], s[kvb][1]), y0 = cvtpk(s[kvb][4], s[kvb][5]);
            u32 x1 = cvtpk(s[kvb][2], s[kvb][3]), y1 = cvtpk(s[kvb][6], s[kvb][7]);
            u32 x2 = cvtpk(s[kvb][8], s[kvb][9]), y2 = cvtpk(s[kvb][12], s[kvb][13]);
            u32 x3 = cvtpk(s[kvb][10], s[kvb][11]), y3 = cvtpk(s[kvb][14], s[kvb][15]);
            plswap(x0, y0); plswap(x1, y1); plswap(x2, y2); plswap(x3, y3);
            u32x4v plo = {x0, x1, y0, y1};
            u32x4v phi = {x2, x3, y2, y3};
            pb[2 * kvb] = __builtin_bit_cast(bf16x8, plo);
            pb[2 * kvb + 1] = __builtin_bit_cast(bf16x8, phi);
        }

        // PV: O^T += V^T * P^T ; lsum via ones-row MFMA
        bf16x8 va[2][4];
#pragma unroll
        for (int db = 0; db < 2; db++)
#pragma unroll
            for (int ks = 0; ks < 4; ks++)
                va[db][ks] = *reinterpret_cast<const bf16x8*>(VL(g, c) + ks * 2048 + db * 1024 + fbase);
        __builtin_amdgcn_s_setprio(1);
#pragma unroll
        for (int ks = 0; ks < 4; ks++) {
            accO[0] = __builtin_amdgcn_mfma_f32_32x32x16_bf16(va[0][ks], pb[ks], accO[0], 0, 0, 0);
            accO[1] = __builtin_amdgcn_mfma_f32_32x32x16_bf16(va[1][ks], pb[ks], accO[1], 0, 0, 0);
            accL = __builtin_amdgcn_mfma_f32_32x32x16_bf16(ones, pb[ks], accL, 0, 0, 0);
        }
        __builtin_amdgcn_s_setprio(0);

        RAW_BAR();  // all waves done reading buf[c] before stage(pp+2) overwrites it
    }
#undef STAGE

    float lsum = accL[0];  // complete row-sum for this kv half

    // merge the two kv groups via LDS (exact: no max involved)
    float* mbuf = (float*)smem;
    int base = (wg * 64 + lane) * 36;  // 144B stride, 16B-aligned
    if (g == 1) {
#pragma unroll
        for (int db = 0; db < 2; db++)
#pragma unroll
            for (int q4 = 0; q4 < 4; q4++) {
                f32x4 v4 = {accO[db][q4 * 4 + 0], accO[db][q4 * 4 + 1],
                            accO[db][q4 * 4 + 2], accO[db][q4 * 4 + 3]};
                *reinterpret_cast<f32x4*>(mbuf + base + db * 16 + q4 * 4) = v4;
            }
        mbuf[base + 32] = lsum;
    }
    __syncthreads();
    if (g == 0) {
        float lsum2 = mbuf[base + 32];
        float inv = 1.f / (lsum + lsum2);
        int b = bh >> 4, h = bh & 15;
        u16* ob = o + ((size_t)(b * 2048 + q0 + l31)) * 1024 + h * 64;
#pragma unroll
        for (int db = 0; db < 2; db++) {
            f32x4 m4[4];
#pragma unroll
            for (int q4 = 0; q4 < 4; q4++)
                m4[q4] = *reinterpret_cast<const f32x4*>(mbuf + base + db * 16 + q4 * 4);
#pragma unroll
            for (int i = 0; i < 8; i++) {
                int r = 2 * i;
                int d = (r & 3) + 8 * (r >> 2) + 4 * hi + 32 * db;
                float lo = (accO[db][r] + m4[r >> 2][r & 3]) * inv;
                float hi_ = (accO[db][r + 1] + m4[(r + 1) >> 2][(r + 1) & 3]) * inv;
                *reinterpret_cast<u32*>(ob + d) = cvtpk(lo, hi_);
            }
        }
    }
#undef KL
#undef VL
}

// ---------------- launch ----------------

extern "C" void kernel_launch(void* const* d_in, const int* in_sizes, int n_in,
                              void* d_out, int out_size, void* d_ws, size_t ws_size,
                              hipStream_t stream) {
    (void)in_sizes; (void)n_in; (void)out_size; (void)ws_size;
    const float* x = (const float*)d_in[0];
    const float* w_qkv = (const float*)d_in[1];
    const float* w_proj = (const float*)d_in[2];
    const float* b_proj = (const float*)d_in[3];
    float* out = (float*)d_out;
    char* ws = (char*)d_ws;

    u16* xb   = (u16*)(ws + 0);            // 4096x1024 bf16
    u16* wqt  = (u16*)(ws + 8388608);      // 3072x1024 bf16
    u16* wpt  = (u16*)(ws + 14680064);     // 1024x1024 bf16
    u16* qws  = (u16*)(ws + 16777216);     // [32][2048][64] bf16 (pre-scaled by 0.125*log2e)
    u16* kws  = (u16*)(ws + 25165824);
    u16* vtws = (u16*)(ws + 41943040);     // [32][64][2048] bf16 (written transposed by GEMM1)
    u16* attn = (u16*)(ws + 50331648);     // [4096][1024] bf16

    prep_kernel<<<6144, 256, 0, stream>>>(x, xb, w_qkv, wqt, w_proj, wpt);
    gemm1_kernel<<<1536, 256, 0, stream>>>(xb, wqt, qws, kws, vtws);
    flash6_kernel<<<dim3(16, 32), 512, 0, stream>>>(qws, kws, vtws, attn);
    gemm2_kernel<<<1024, 256, 0, stream>>>(attn, wpt, out, b_proj);
}

// Round 13
// 98.547 us; speedup vs baseline: 1.3675x; 1.3675x over previous
//
#include <hip/hip_runtime.h>
#include <stdint.h>

// MultiHeadSelfAttention: x[2,2048,1024] fp32, w_qkv[1024,3072], w_proj[1024,1024], b_proj[1024]
// prep(cvt+trw) -> GEMM1(qkv, 128x128 tile, 3 blk/CU, gload_lds, XCD strips, V transposed) ->
// flash6 (swapped-operand, chunked LDS, fixed-max softmax, kv-split x2, MFMA-lsum) ->
// GEMM2(+bias, 64x64 tile, 4 blk/CU)

typedef unsigned short u16;
typedef uint32_t u32;
typedef __bf16 bf16x8 __attribute__((ext_vector_type(8)));
typedef unsigned short u16x8 __attribute__((ext_vector_type(8)));
typedef float f32x4 __attribute__((ext_vector_type(4)));
typedef float f32x16 __attribute__((ext_vector_type(16)));
typedef uint32_t u32x2v __attribute__((ext_vector_type(2)));
typedef uint32_t u32x4v __attribute__((ext_vector_type(4)));

#define DEV static __device__ __forceinline__

DEV u16 f2bf(float f) {
    uint32_t u = __float_as_uint(f);
    u += 0x7fffu + ((u >> 16) & 1u);
    return (u16)(u >> 16);
}

DEV u32 cvtpk(float lo, float hi_) {
    u32 r;
    asm("v_cvt_pk_bf16_f32 %0, %1, %2" : "=v"(r) : "v"(lo), "v"(hi_));
    return r;
}
DEV void plswap(u32& x, u32& y) {
    asm("v_permlane32_swap_b32 %0, %1" : "+v"(x), "+v"(y));
}
DEV float exp2f_fast(float x) {
    float r;
    asm("v_exp_f32 %0, %1" : "=v"(r) : "v"(x));
    return r;
}

DEV void gload_lds16(const void* g, void* l) {
    __builtin_amdgcn_global_load_lds(
        (const __attribute__((address_space(1))) uint32_t*)g,
        (__attribute__((address_space(3))) uint32_t*)l, 16, 0, 0);
}

#define WAIT_VM(N) asm volatile("s_waitcnt vmcnt(" #N ")" ::: "memory")
#define RAW_BAR() __builtin_amdgcn_s_barrier()
#define SCHED_PIN() __builtin_amdgcn_sched_barrier(0)

// GEMM LDS read: [row][64] bf16 rows (128B), XOR swizzle byte ^= (row&7)<<4.
DEV bf16x8 swz_load16(const u16* base, int row, int kbyte) {
    int off = (row * 128 + kbyte) ^ ((row & 7) << 4);
    return *reinterpret_cast<const bf16x8*>(reinterpret_cast<const char*>(base) + off);
}

// ---------------- prep: cvt_x + transpose both weights (fused, one launch) ----------------
__global__ __launch_bounds__(256) void prep_kernel(
    const float* __restrict__ x, u16* __restrict__ xb,
    const float* __restrict__ wq, u16* __restrict__ wqt,
    const float* __restrict__ wp, u16* __restrict__ wpt) {
    __shared__ float T[32][33];
    int b = blockIdx.x, tid = threadIdx.x;
    if (b < 2048) {
        int t = b * 256 + tid;
        const float4* p = reinterpret_cast<const float4*>(x) + (size_t)t * 2;
        float4 a = p[0], c = p[1];
        u16x8 o;
        o[0] = f2bf(a.x); o[1] = f2bf(a.y); o[2] = f2bf(a.z); o[3] = f2bf(a.w);
        o[4] = f2bf(c.x); o[5] = f2bf(c.y); o[6] = f2bf(c.z); o[7] = f2bf(c.w);
        reinterpret_cast<u16x8*>(xb)[t] = o;
        return;
    }
    const float* in;
    u16* out;
    int bx, by, R = 1024, Cc;
    if (b < 5120) {
        int idx = b - 2048;
        bx = idx % 96; by = idx / 96; Cc = 3072; in = wq; out = wqt;
    } else {
        int idx = b - 5120;
        bx = idx % 32; by = idx / 32; Cc = 1024; in = wp; out = wpt;
    }
    int tx = tid & 31, ty = tid >> 5;
    int xcol = bx * 32 + tx;
    int y0 = by * 32;
#pragma unroll
    for (int i = 0; i < 4; i++) {
        int y = y0 + ty + i * 8;
        T[ty + i * 8][tx] = in[(size_t)y * Cc + xcol];
    }
    __syncthreads();
    int xo = y0 + tx;
    int yo0 = bx * 32;
#pragma unroll
    for (int i = 0; i < 4; i++) {
        int yo = yo0 + ty + i * 8;
        out[(size_t)yo * R + xo] = f2bf(T[tx][ty + i * 8]);
    }
}

// ---------------- GEMM1: xb[4096,1024] x wqt[3072,1024]^T, 128x128 tile, 4 waves ----------------
// Single-buf gload_lds staging, XCD strips (xcd = p&7, 4 bm-rows/XCD). Epilogue scatters
// q (scaled by 0.125*log2e), k row-major, v transposed (vt[bh][d][n]).
__global__ __launch_bounds__(256, 2) void gemm1_kernel(
    const u16* __restrict__ A, const u16* __restrict__ Bt,
    u16* __restrict__ o_q, u16* __restrict__ o_k, u16* __restrict__ o_vt) {
    __shared__ __align__(16) u16 Al[8192];
    __shared__ __align__(16) u16 Bl[8192];
    int tid = threadIdx.x;
    int p = blockIdx.x;
    int xcd = p & 7, q = p >> 3;
    int bm = xcd * 4 + q / 24, bn = q % 24;
    int lane = tid & 63, w = tid >> 6;
    int wr = w >> 1, wc = w & 1;
    int l15 = lane & 15, lhi = lane >> 4;

    f32x4 acc[4][4];
#pragma unroll
    for (int i = 0; i < 4; i++)
#pragma unroll
        for (int j = 0; j < 4; j++) acc[i][j] = (f32x4){0.f, 0.f, 0.f, 0.f};

    for (int kt = 0; kt < 16; ++kt) {
#pragma unroll
        for (int i = 0; i < 4; i++) {
            int lin = w * 4096 + i * 1024 + lane * 16;
            int row = lin >> 7;
            int src = (lin & 127) ^ ((row & 7) << 4);
            gload_lds16((const char*)A + (size_t)(bm * 128 + row) * 2048 + (size_t)kt * 128 + src,
                        (char*)Al + lin);
            gload_lds16((const char*)Bt + (size_t)(bn * 128 + row) * 2048 + (size_t)kt * 128 + src,
                        (char*)Bl + lin);
        }
        __syncthreads();
#pragma unroll
        for (int ks = 0; ks < 2; ++ks) {
            bf16x8 af[4], bfr[4];
#pragma unroll
            for (int mi = 0; mi < 4; ++mi) af[mi] = swz_load16(Al, wr * 64 + mi * 16 + l15, ks * 64 + lhi * 16);
#pragma unroll
            for (int ni = 0; ni < 4; ++ni) bfr[ni] = swz_load16(Bl, wc * 64 + ni * 16 + l15, ks * 64 + lhi * 16);
            __builtin_amdgcn_s_setprio(1);
#pragma unroll
            for (int mi = 0; mi < 4; ++mi)
#pragma unroll
                for (int ni = 0; ni < 4; ++ni)
                    acc[mi][ni] = __builtin_amdgcn_mfma_f32_16x16x32_bf16(af[mi], bfr[ni], acc[mi][ni], 0, 0, 0);
            __builtin_amdgcn_s_setprio(0);
        }
        __syncthreads();
    }

    int row0 = bm * 128 + wr * 64, col0 = bn * 128 + wc * 64;
#pragma unroll
    for (int mi = 0; mi < 4; mi++)
#pragma unroll
        for (int ni = 0; ni < 4; ni++) {
            int col = col0 + ni * 16 + l15;
            int sel = col >> 10, cc = col & 1023;
            int h = cc >> 6, d = cc & 63;
            int r0 = row0 + mi * 16 + lhi * 4;
            int b = r0 >> 11, n0 = r0 & 2047;
            if (sel == 2) {
                u32x2v pk2 = {cvtpk(acc[mi][ni][0], acc[mi][ni][1]),
                              cvtpk(acc[mi][ni][2], acc[mi][ni][3])};
                *reinterpret_cast<u32x2v*>(o_vt + ((size_t)(b * 16 + h) * 64 + d) * 2048 + n0) = pk2;
            } else {
                size_t base = (((size_t)(b * 16 + h)) * 2048 + n0) * 64 + d;
#pragma unroll
                for (int j = 0; j < 4; j++) {
                    float v = acc[mi][ni][j];
                    if (sel == 0) o_q[base + (size_t)j * 64] = f2bf(v * 0.18033688f);  // 0.125*log2e
                    else o_k[base + (size_t)j * 64] = f2bf(v);
                }
            }
        }
}

// ---------------- GEMM2: attn[4096,1024] x wpt[1024,1024]^T + bias, 64x64 tile, 4 waves ----------------
__global__ __launch_bounds__(256, 4) void gemm2_kernel(
    const u16* __restrict__ A, const u16* __restrict__ Bt,
    float* __restrict__ o_f, const float* __restrict__ bias) {
    __shared__ __align__(16) u16 Al[4096];
    __shared__ __align__(16) u16 Bl[4096];
    int tid = threadIdx.x;
    int p = blockIdx.x;
    int xcd = p & 7, q = p >> 3;
    int bm = xcd * 8 + q / 16, bn = q % 16;
    int lane = tid & 63, w = tid >> 6;
    int wr = w >> 1, wc = w & 1;
    int l15 = lane & 15, lhi = lane >> 4;

    f32x4 acc[2][2];
#pragma unroll
    for (int i = 0; i < 2; i++)
#pragma unroll
        for (int j = 0; j < 2; j++) acc[i][j] = (f32x4){0.f, 0.f, 0.f, 0.f};

    for (int kt = 0; kt < 16; ++kt) {
#pragma unroll
        for (int i = 0; i < 2; i++) {
            int lin = tid * 16 + i * 4096;
            int row = lin >> 7;
            int src = (lin & 127) ^ ((row & 7) << 4);
            gload_lds16((const char*)A + (size_t)(bm * 64 + row) * 2048 + (size_t)kt * 128 + src,
                        (char*)Al + lin);
            gload_lds16((const char*)Bt + (size_t)(bn * 64 + row) * 2048 + (size_t)kt * 128 + src,
                        (char*)Bl + lin);
        }
        __syncthreads();
#pragma unroll
        for (int ks = 0; ks < 2; ++ks) {
            bf16x8 af[2], bfr[2];
#pragma unroll
            for (int mi = 0; mi < 2; ++mi) af[mi] = swz_load16(Al, wr * 32 + mi * 16 + l15, ks * 64 + lhi * 16);
#pragma unroll
            for (int ni = 0; ni < 2; ++ni) bfr[ni] = swz_load16(Bl, wc * 32 + ni * 16 + l15, ks * 64 + lhi * 16);
            __builtin_amdgcn_s_setprio(1);
#pragma unroll
            for (int mi = 0; mi < 2; ++mi)
#pragma unroll
                for (int ni = 0; ni < 2; ++ni)
                    acc[mi][ni] = __builtin_amdgcn_mfma_f32_16x16x32_bf16(af[mi], bfr[ni], acc[mi][ni], 0, 0, 0);
            __builtin_amdgcn_s_setprio(0);
        }
        __syncthreads();
    }

    int row0 = bm * 64 + wr * 32, col0 = bn * 64 + wc * 32;
#pragma unroll
    for (int mi = 0; mi < 2; mi++)
#pragma unroll
        for (int ni = 0; ni < 2; ni++) {
            int col = col0 + ni * 16 + l15;
            float bb = bias[col];
#pragma unroll
            for (int j = 0; j < 4; j++) {
                int r = row0 + mi * 16 + lhi * 4 + j;
                o_f[(size_t)r * 1024 + col] = acc[mi][ni][j] + bb;
            }
        }
}

// ---------------- flash6: fixed-max softmax + kv-split x2, zero-C MFMA + MFMA-lsum ----------------
__global__ __launch_bounds__(512, 4) void flash6_kernel(
    const u16* __restrict__ qg, const u16* __restrict__ kg, const u16* __restrict__ vtg,
    u16* __restrict__ o) {
    __shared__ __align__(16) char smem[65536];

    int tid = threadIdx.x, lane = tid & 63, w = tid >> 6;
    int wg = w & 3, g = w >> 2;
    int l31 = lane & 31, hi = lane >> 5;
    int p = blockIdx.y * 16 + blockIdx.x;
    int bh = p & 31, qt = p >> 5;  // p%8 = XCD: each XCD sees 4 distinct bh -> K/V L2-local
    int q0 = qt * 128 + wg * 32;

#define KL(gg, bb) (smem + ((gg) * 2 + (bb)) * 8192)
#define VL(gg, bb) (smem + 32768 + ((gg) * 2 + (bb)) * 8192)

    const u16* qp = qg + ((size_t)bh * 2048 + q0 + l31) * 64 + hi * 8;
    bf16x8 qf[4];
#pragma unroll
    for (int ds = 0; ds < 4; ds++) qf[ds] = *reinterpret_cast<const bf16x8*>(qp + ds * 16);

    const char* kbg = (const char*)(kg + (size_t)bh * 2048 * 64) + (size_t)g * 16 * 8192;
    const char* vbg = (const char*)(vtg + (size_t)bh * 64 * 2048) + (size_t)g * 2048;

    int srow = lane >> 1, sinner = (lane & 1) * 16;
    int fbase = l31 * 32 + hi * 16;

#define STAGE(bb, tt)                                                                     \
    {                                                                                     \
        _Pragma("unroll") for (int i = 0; i < 2; i++) {                                   \
            gload_lds16(kbg + (size_t)(tt) * 8192 + (i * 32 + srow) * 128 + wg * 32 + sinner, \
                        KL(g, bb) + wg * 2048 + i * 1024 + lane * 16);                    \
            gload_lds16(vbg + (size_t)(i * 32 + srow) * 4096 + (size_t)(tt) * 128 + wg * 32 + sinner, \
                        VL(g, bb) + wg * 2048 + i * 1024 + lane * 16);                    \
        }                                                                                 \
    }

    f32x16 fzero;
#pragma unroll
    for (int r = 0; r < 16; r++) fzero[r] = 0.f;
    f32x16 accO[2], accL;
#pragma unroll
    for (int db = 0; db < 2; db++) accO[db] = fzero;
    accL = fzero;
    u16x8 ou;
#pragma unroll
    for (int j = 0; j < 8; j++) ou[j] = 0x3F80;  // bf16 1.0
    bf16x8 ones = __builtin_bit_cast(bf16x8, ou);

    STAGE(0, 0);

    for (int pp = 0; pp < 16; ++pp) {
        int c = pp & 1;
        if (pp < 15) {
            STAGE(c ^ 1, pp + 1);  // 4 loads stay in flight across the barrier
            WAIT_VM(4);            // wait only stage(pp)
        } else {
            WAIT_VM(0);
        }
        RAW_BAR();
        SCHED_PIN();

        // QK: S^T = K * Q^T
        bf16x8 ka[2][4];
#pragma unroll
        for (int kvb = 0; kvb < 2; kvb++)
#pragma unroll
            for (int ds = 0; ds < 4; ds++)
                ka[kvb][ds] = *reinterpret_cast<const bf16x8*>(KL(g, c) + ds * 2048 + kvb * 1024 + fbase);
        f32x16 s[2];
        __builtin_amdgcn_s_setprio(1);
#pragma unroll
        for (int kvb = 0; kvb < 2; kvb++) {
            s[kvb] = __builtin_amdgcn_mfma_f32_32x32x16_bf16(ka[kvb][0], qf[0], fzero, 0, 0, 0);
#pragma unroll
            for (int ds = 1; ds < 4; ds++)
                s[kvb] = __builtin_amdgcn_mfma_f32_32x32x16_bf16(ka[kvb][ds], qf[ds], s[kvb], 0, 0, 0);
        }
        __builtin_amdgcn_s_setprio(0);

        // fixed-max softmax: P = exp2(s)  (Q pre-scaled by 0.125*log2e)
#pragma unroll
        for (int kvb = 0; kvb < 2; kvb++)
#pragma unroll
            for (int r = 0; r < 16; r++) s[kvb][r] = exp2f_fast(s[kvb][r]);

        // P^T B-frags in-register
        bf16x8 pb[4];
#pragma unroll
        for (int kvb = 0; kvb < 2; kvb++) {
            u32 x0 = cvtpk(s[kvb][0], s[kvb][1]), y0 = cvtpk(s[kvb][4], s[kvb][5]);
            u32 x1 = cvtpk(s[kvb][2], s[kvb][3]), y1 = cvtpk(s[kvb][6], s[kvb][7]);
            u32 x2 = cvtpk(s[kvb][8], s[kvb][9]), y2 = cvtpk(s[kvb][12], s[kvb][13]);
            u32 x3 = cvtpk(s[kvb][10], s[kvb][11]), y3 = cvtpk(s[kvb][14], s[kvb][15]);
            plswap(x0, y0); plswap(x1, y1); plswap(x2, y2); plswap(x3, y3);
            u32x4v plo = {x0, x1, y0, y1};
            u32x4v phi = {x2, x3, y2, y3};
            pb[2 * kvb] = __builtin_bit_cast(bf16x8, plo);
            pb[2 * kvb + 1] = __builtin_bit_cast(bf16x8, phi);
        }

        // PV: O^T += V^T * P^T ; lsum via ones-row MFMA
        bf16x8 va[2][4];
#pragma unroll
        for (int db = 0; db < 2; db++)
#pragma unroll
            for (int ks = 0; ks < 4; ks++)
                va[db][ks] = *reinterpret_cast<const bf16x8*>(VL(g, c) + ks * 2048 + db * 1024 + fbase);
        __builtin_amdgcn_s_setprio(1);
#pragma unroll
        for (int ks = 0; ks < 4; ks++) {
            accO[0] = __builtin_amdgcn_mfma_f32_32x32x16_bf16(va[0][ks], pb[ks], accO[0], 0, 0, 0);
            accO[1] = __builtin_amdgcn_mfma_f32_32x32x16_bf16(va[1][ks], pb[ks], accO[1], 0, 0, 0);
            accL = __builtin_amdgcn_mfma_f32_32x32x16_bf16(ones, pb[ks], accL, 0, 0, 0);
        }
        __builtin_amdgcn_s_setprio(0);

        RAW_BAR();  // all waves done reading buf[c] before stage(pp+2) overwrites it
    }
#undef STAGE

    float lsum = accL[0];  // complete row-sum for this kv half

    // merge the two kv groups via LDS (exact: no max involved)
    float* mbuf = (float*)smem;
    int base = (wg * 64 + lane) * 36;  // 144B stride, 16B-aligned
    if (g == 1) {
#pragma unroll
        for (int db = 0; db < 2; db++)
#pragma unroll
            for (int q4 = 0; q4 < 4; q4++) {
                f32x4 v4 = {accO[db][q4 * 4 + 0], accO[db][q4 * 4 + 1],
                            accO[db][q4 * 4 + 2], accO[db][q4 * 4 + 3]};
                *reinterpret_cast<f32x4*>(mbuf + base + db * 16 + q4 * 4) = v4;
            }
        mbuf[base + 32] = lsum;
    }
    __syncthreads();
    if (g == 0) {
        float lsum2 = mbuf[base + 32];
        float inv = 1.f / (lsum + lsum2);
        int b = bh >> 4, h = bh & 15;
        u16* ob = o + ((size_t)(b * 2048 + q0 + l31)) * 1024 + h * 64;
#pragma unroll
        for (int db = 0; db < 2; db++) {
            f32x4 m4[4];
#pragma unroll
            for (int q4 = 0; q4 < 4; q4++)
                m4[q4] = *reinterpret_cast<const f32x4*>(mbuf + base + db * 16 + q4 * 4);
#pragma unroll
            for (int i = 0; i < 8; i++) {
                int r = 2 * i;
                int d = (r & 3) + 8 * (r >> 2) + 4 * hi + 32 * db;
                float lo = (accO[db][r] + m4[r >> 2][r & 3]) * inv;
                float hi_ = (accO[db][r + 1] + m4[(r + 1) >> 2][(r + 1) & 3]) * inv;
                *reinterpret_cast<u32*>(ob + d) = cvtpk(lo, hi_);
            }
        }
    }
#undef KL
#undef VL
}

// ---------------- launch ----------------

extern "C" void kernel_launch(void* const* d_in, const int* in_sizes, int n_in,
                              void* d_out, int out_size, void* d_ws, size_t ws_size,
                              hipStream_t stream) {
    (void)in_sizes; (void)n_in; (void)out_size; (void)ws_size;
    const float* x = (const float*)d_in[0];
    const float* w_qkv = (const float*)d_in[1];
    const float* w_proj = (const float*)d_in[2];
    const float* b_proj = (const float*)d_in[3];
    float* out = (float*)d_out;
    char* ws = (char*)d_ws;

    u16* xb   = (u16*)(ws + 0);            // 4096x1024 bf16
    u16* wqt  = (u16*)(ws + 8388608);      // 3072x1024 bf16
    u16* wpt  = (u16*)(ws + 14680064);     // 1024x1024 bf16
    u16* qws  = (u16*)(ws + 16777216);     // [32][2048][64] bf16 (pre-scaled by 0.125*log2e)
    u16* kws  = (u16*)(ws + 25165824);
    u16* vtws = (u16*)(ws + 41943040);     // [32][64][2048] bf16 (written transposed by GEMM1)
    u16* attn = (u16*)(ws + 50331648);     // [4096][1024] bf16

    prep_kernel<<<6144, 256, 0, stream>>>(x, xb, w_qkv, wqt, w_proj, wpt);
    gemm1_kernel<<<768, 256, 0, stream>>>(xb, wqt, qws, kws, vtws);
    flash6_kernel<<<dim3(16, 32), 512, 0, stream>>>(qws, kws, vtws, attn);
    gemm2_kernel<<<1024, 256, 0, stream>>>(attn, wpt, out, b_proj);
}

// Round 14
// 98.370 us; speedup vs baseline: 1.3700x; 1.0018x over previous
//
#include <hip/hip_runtime.h>
#include <stdint.h>

// MultiHeadSelfAttention: x[2,2048,1024] fp32, w_qkv[1024,3072], w_proj[1024,1024], b_proj[1024]
// prep(cvt+trw) -> GEMM1(qkv, 128x128 tile, XCD strips, bn-outer/bm-inner B-reuse order,
// V transposed) -> flash6 (swapped-operand, chunked LDS, fixed-max softmax, kv-split x2,
// MFMA-lsum) -> GEMM2(+bias, 64x64 tile)

typedef unsigned short u16;
typedef uint32_t u32;
typedef __bf16 bf16x8 __attribute__((ext_vector_type(8)));
typedef unsigned short u16x8 __attribute__((ext_vector_type(8)));
typedef float f32x4 __attribute__((ext_vector_type(4)));
typedef float f32x16 __attribute__((ext_vector_type(16)));
typedef uint32_t u32x2v __attribute__((ext_vector_type(2)));
typedef uint32_t u32x4v __attribute__((ext_vector_type(4)));

#define DEV static __device__ __forceinline__

DEV u16 f2bf(float f) {
    uint32_t u = __float_as_uint(f);
    u += 0x7fffu + ((u >> 16) & 1u);
    return (u16)(u >> 16);
}

DEV u32 cvtpk(float lo, float hi_) {
    u32 r;
    asm("v_cvt_pk_bf16_f32 %0, %1, %2" : "=v"(r) : "v"(lo), "v"(hi_));
    return r;
}
DEV void plswap(u32& x, u32& y) {
    asm("v_permlane32_swap_b32 %0, %1" : "+v"(x), "+v"(y));
}
DEV float exp2f_fast(float x) {
    float r;
    asm("v_exp_f32 %0, %1" : "=v"(r) : "v"(x));
    return r;
}

DEV void gload_lds16(const void* g, void* l) {
    __builtin_amdgcn_global_load_lds(
        (const __attribute__((address_space(1))) uint32_t*)g,
        (__attribute__((address_space(3))) uint32_t*)l, 16, 0, 0);
}

#define WAIT_VM(N) asm volatile("s_waitcnt vmcnt(" #N ")" ::: "memory")
#define RAW_BAR() __builtin_amdgcn_s_barrier()
#define SCHED_PIN() __builtin_amdgcn_sched_barrier(0)

// GEMM LDS read: [row][64] bf16 rows (128B), XOR swizzle byte ^= (row&7)<<4.
DEV bf16x8 swz_load16(const u16* base, int row, int kbyte) {
    int off = (row * 128 + kbyte) ^ ((row & 7) << 4);
    return *reinterpret_cast<const bf16x8*>(reinterpret_cast<const char*>(base) + off);
}

// ---------------- prep: cvt_x + transpose both weights (fused, one launch) ----------------
__global__ __launch_bounds__(256) void prep_kernel(
    const float* __restrict__ x, u16* __restrict__ xb,
    const float* __restrict__ wq, u16* __restrict__ wqt,
    const float* __restrict__ wp, u16* __restrict__ wpt) {
    __shared__ float T[32][33];
    int b = blockIdx.x, tid = threadIdx.x;
    if (b < 2048) {
        int t = b * 256 + tid;
        const float4* p = reinterpret_cast<const float4*>(x) + (size_t)t * 2;
        float4 a = p[0], c = p[1];
        u16x8 o;
        o[0] = f2bf(a.x); o[1] = f2bf(a.y); o[2] = f2bf(a.z); o[3] = f2bf(a.w);
        o[4] = f2bf(c.x); o[5] = f2bf(c.y); o[6] = f2bf(c.z); o[7] = f2bf(c.w);
        reinterpret_cast<u16x8*>(xb)[t] = o;
        return;
    }
    const float* in;
    u16* out;
    int bx, by, R = 1024, Cc;
    if (b < 5120) {
        int idx = b - 2048;
        bx = idx % 96; by = idx / 96; Cc = 3072; in = wq; out = wqt;
    } else {
        int idx = b - 5120;
        bx = idx % 32; by = idx / 32; Cc = 1024; in = wp; out = wpt;
    }
    int tx = tid & 31, ty = tid >> 5;
    int xcol = bx * 32 + tx;
    int y0 = by * 32;
#pragma unroll
    for (int i = 0; i < 4; i++) {
        int y = y0 + ty + i * 8;
        T[ty + i * 8][tx] = in[(size_t)y * Cc + xcol];
    }
    __syncthreads();
    int xo = y0 + tx;
    int yo0 = bx * 32;
#pragma unroll
    for (int i = 0; i < 4; i++) {
        int yo = yo0 + ty + i * 8;
        out[(size_t)yo * R + xo] = f2bf(T[tx][ty + i * 8]);
    }
}

// ---------------- GEMM1: xb[4096,1024] x wqt[3072,1024]^T, 128x128 tile, 4 waves ----------------
// bn-outer/bm-inner within XCD: 4 consecutive blocks share one B panel (L2-hit); the 1 MB A
// strip stays L2-resident across all 96 blocks of the XCD.
__global__ __launch_bounds__(256, 2) void gemm1_kernel(
    const u16* __restrict__ A, const u16* __restrict__ Bt,
    u16* __restrict__ o_q, u16* __restrict__ o_k, u16* __restrict__ o_vt) {
    __shared__ __align__(16) u16 Al[8192];
    __shared__ __align__(16) u16 Bl[8192];
    int tid = threadIdx.x;
    int p = blockIdx.x;
    int xcd = p & 7, q = p >> 3;
    int bm = xcd * 4 + (q & 3), bn = q >> 2;   // bm-inner: B panel reused by 4 consecutive blocks
    int lane = tid & 63, w = tid >> 6;
    int wr = w >> 1, wc = w & 1;
    int l15 = lane & 15, lhi = lane >> 4;

    f32x4 acc[4][4];
#pragma unroll
    for (int i = 0; i < 4; i++)
#pragma unroll
        for (int j = 0; j < 4; j++) acc[i][j] = (f32x4){0.f, 0.f, 0.f, 0.f};

    for (int kt = 0; kt < 16; ++kt) {
#pragma unroll
        for (int i = 0; i < 4; i++) {
            int lin = w * 4096 + i * 1024 + lane * 16;
            int row = lin >> 7;
            int src = (lin & 127) ^ ((row & 7) << 4);
            gload_lds16((const char*)A + (size_t)(bm * 128 + row) * 2048 + (size_t)kt * 128 + src,
                        (char*)Al + lin);
            gload_lds16((const char*)Bt + (size_t)(bn * 128 + row) * 2048 + (size_t)kt * 128 + src,
                        (char*)Bl + lin);
        }
        __syncthreads();
#pragma unroll
        for (int ks = 0; ks < 2; ++ks) {
            bf16x8 af[4], bfr[4];
#pragma unroll
            for (int mi = 0; mi < 4; ++mi) af[mi] = swz_load16(Al, wr * 64 + mi * 16 + l15, ks * 64 + lhi * 16);
#pragma unroll
            for (int ni = 0; ni < 4; ++ni) bfr[ni] = swz_load16(Bl, wc * 64 + ni * 16 + l15, ks * 64 + lhi * 16);
            __builtin_amdgcn_s_setprio(1);
#pragma unroll
            for (int mi = 0; mi < 4; ++mi)
#pragma unroll
                for (int ni = 0; ni < 4; ++ni)
                    acc[mi][ni] = __builtin_amdgcn_mfma_f32_16x16x32_bf16(af[mi], bfr[ni], acc[mi][ni], 0, 0, 0);
            __builtin_amdgcn_s_setprio(0);
        }
        __syncthreads();
    }

    int row0 = bm * 128 + wr * 64, col0 = bn * 128 + wc * 64;
#pragma unroll
    for (int mi = 0; mi < 4; mi++)
#pragma unroll
        for (int ni = 0; ni < 4; ni++) {
            int col = col0 + ni * 16 + l15;
            int sel = col >> 10, cc = col & 1023;
            int h = cc >> 6, d = cc & 63;
            int r0 = row0 + mi * 16 + lhi * 4;
            int b = r0 >> 11, n0 = r0 & 2047;
            if (sel == 2) {
                u32x2v pk2 = {cvtpk(acc[mi][ni][0], acc[mi][ni][1]),
                              cvtpk(acc[mi][ni][2], acc[mi][ni][3])};
                *reinterpret_cast<u32x2v*>(o_vt + ((size_t)(b * 16 + h) * 64 + d) * 2048 + n0) = pk2;
            } else {
                size_t base = (((size_t)(b * 16 + h)) * 2048 + n0) * 64 + d;
#pragma unroll
                for (int j = 0; j < 4; j++) {
                    float v = acc[mi][ni][j];
                    if (sel == 0) o_q[base + (size_t)j * 64] = f2bf(v * 0.18033688f);  // 0.125*log2e
                    else o_k[base + (size_t)j * 64] = f2bf(v);
                }
            }
        }
}

// ---------------- GEMM2: attn[4096,1024] x wpt[1024,1024]^T + bias, 64x64 tile, 4 waves ----------------
__global__ __launch_bounds__(256, 4) void gemm2_kernel(
    const u16* __restrict__ A, const u16* __restrict__ Bt,
    float* __restrict__ o_f, const float* __restrict__ bias) {
    __shared__ __align__(16) u16 Al[4096];
    __shared__ __align__(16) u16 Bl[4096];
    int tid = threadIdx.x;
    int p = blockIdx.x;
    int xcd = p & 7, q = p >> 3;
    int bm = xcd * 8 + (q & 7), bn = q >> 3;   // bm-inner B-reuse order
    int lane = tid & 63, w = tid >> 6;
    int wr = w >> 1, wc = w & 1;
    int l15 = lane & 15, lhi = lane >> 4;

    f32x4 acc[2][2];
#pragma unroll
    for (int i = 0; i < 2; i++)
#pragma unroll
        for (int j = 0; j < 2; j++) acc[i][j] = (f32x4){0.f, 0.f, 0.f, 0.f};

    for (int kt = 0; kt < 16; ++kt) {
#pragma unroll
        for (int i = 0; i < 2; i++) {
            int lin = tid * 16 + i * 4096;
            int row = lin >> 7;
            int src = (lin & 127) ^ ((row & 7) << 4);
            gload_lds16((const char*)A + (size_t)(bm * 64 + row) * 2048 + (size_t)kt * 128 + src,
                        (char*)Al + lin);
            gload_lds16((const char*)Bt + (size_t)(bn * 64 + row) * 2048 + (size_t)kt * 128 + src,
                        (char*)Bl + lin);
        }
        __syncthreads();
#pragma unroll
        for (int ks = 0; ks < 2; ++ks) {
            bf16x8 af[2], bfr[2];
#pragma unroll
            for (int mi = 0; mi < 2; ++mi) af[mi] = swz_load16(Al, wr * 32 + mi * 16 + l15, ks * 64 + lhi * 16);
#pragma unroll
            for (int ni = 0; ni < 2; ++ni) bfr[ni] = swz_load16(Bl, wc * 32 + ni * 16 + l15, ks * 64 + lhi * 16);
            __builtin_amdgcn_s_setprio(1);
#pragma unroll
            for (int mi = 0; mi < 2; ++mi)
#pragma unroll
                for (int ni = 0; ni < 2; ++ni)
                    acc[mi][ni] = __builtin_amdgcn_mfma_f32_16x16x32_bf16(af[mi], bfr[ni], acc[mi][ni], 0, 0, 0);
            __builtin_amdgcn_s_setprio(0);
        }
        __syncthreads();
    }

    int row0 = bm * 64 + wr * 32, col0 = bn * 64 + wc * 32;
#pragma unroll
    for (int mi = 0; mi < 2; mi++)
#pragma unroll
        for (int ni = 0; ni < 2; ni++) {
            int col = col0 + ni * 16 + l15;
            float bb = bias[col];
#pragma unroll
            for (int j = 0; j < 4; j++) {
                int r = row0 + mi * 16 + lhi * 4 + j;
                o_f[(size_t)r * 1024 + col] = acc[mi][ni][j] + bb;
            }
        }
}

// ---------------- flash6: fixed-max softmax + kv-split x2, zero-C MFMA + MFMA-lsum ----------------
__global__ __launch_bounds__(512, 4) void flash6_kernel(
    const u16* __restrict__ qg, const u16* __restrict__ kg, const u16* __restrict__ vtg,
    u16* __restrict__ o) {
    __shared__ __align__(16) char smem[65536];

    int tid = threadIdx.x, lane = tid & 63, w = tid >> 6;
    int wg = w & 3, g = w >> 2;
    int l31 = lane & 31, hi = lane >> 5;
    int p = blockIdx.y * 16 + blockIdx.x;
    int bh = p & 31, qt = p >> 5;  // p%8 = XCD: each XCD sees 4 distinct bh -> K/V L2-local
    int q0 = qt * 128 + wg * 32;

#define KL(gg, bb) (smem + ((gg) * 2 + (bb)) * 8192)
#define VL(gg, bb) (smem + 32768 + ((gg) * 2 + (bb)) * 8192)

    const u16* qp = qg + ((size_t)bh * 2048 + q0 + l31) * 64 + hi * 8;
    bf16x8 qf[4];
#pragma unroll
    for (int ds = 0; ds < 4; ds++) qf[ds] = *reinterpret_cast<const bf16x8*>(qp + ds * 16);

    const char* kbg = (const char*)(kg + (size_t)bh * 2048 * 64) + (size_t)g * 16 * 8192;
    const char* vbg = (const char*)(vtg + (size_t)bh * 64 * 2048) + (size_t)g * 2048;

    int srow = lane >> 1, sinner = (lane & 1) * 16;
    int fbase = l31 * 32 + hi * 16;

#define STAGE(bb, tt)                                                                     \
    {                                                                                     \
        _Pragma("unroll") for (int i = 0; i < 2; i++) {                                   \
            gload_lds16(kbg + (size_t)(tt) * 8192 + (i * 32 + srow) * 128 + wg * 32 + sinner, \
                        KL(g, bb) + wg * 2048 + i * 1024 + lane * 16);                    \
            gload_lds16(vbg + (size_t)(i * 32 + srow) * 4096 + (size_t)(tt) * 128 + wg * 32 + sinner, \
                        VL(g, bb) + wg * 2048 + i * 1024 + lane * 16);                    \
        }                                                                                 \
    }

    f32x16 fzero;
#pragma unroll
    for (int r = 0; r < 16; r++) fzero[r] = 0.f;
    f32x16 accO[2], accL;
#pragma unroll
    for (int db = 0; db < 2; db++) accO[db] = fzero;
    accL = fzero;
    u16x8 ou;
#pragma unroll
    for (int j = 0; j < 8; j++) ou[j] = 0x3F80;  // bf16 1.0
    bf16x8 ones = __builtin_bit_cast(bf16x8, ou);

    STAGE(0, 0);

    for (int pp = 0; pp < 16; ++pp) {
        int c = pp & 1;
        if (pp < 15) {
            STAGE(c ^ 1, pp + 1);  // 4 loads stay in flight across the barrier
            WAIT_VM(4);            // wait only stage(pp)
        } else {
            WAIT_VM(0);
        }
        RAW_BAR();
        SCHED_PIN();

        // QK: S^T = K * Q^T
        bf16x8 ka[2][4];
#pragma unroll
        for (int kvb = 0; kvb < 2; kvb++)
#pragma unroll
            for (int ds = 0; ds < 4; ds++)
                ka[kvb][ds] = *reinterpret_cast<const bf16x8*>(KL(g, c) + ds * 2048 + kvb * 1024 + fbase);
        f32x16 s[2];
        __builtin_amdgcn_s_setprio(1);
#pragma unroll
        for (int kvb = 0; kvb < 2; kvb++) {
            s[kvb] = __builtin_amdgcn_mfma_f32_32x32x16_bf16(ka[kvb][0], qf[0], fzero, 0, 0, 0);
#pragma unroll
            for (int ds = 1; ds < 4; ds++)
                s[kvb] = __builtin_amdgcn_mfma_f32_32x32x16_bf16(ka[kvb][ds], qf[ds], s[kvb], 0, 0, 0);
        }
        __builtin_amdgcn_s_setprio(0);

        // fixed-max softmax: P = exp2(s)  (Q pre-scaled by 0.125*log2e)
#pragma unroll
        for (int kvb = 0; kvb < 2; kvb++)
#pragma unroll
            for (int r = 0; r < 16; r++) s[kvb][r] = exp2f_fast(s[kvb][r]);

        // P^T B-frags in-register
        bf16x8 pb[4];
#pragma unroll
        for (int kvb = 0; kvb < 2; kvb++) {
            u32 x0 = cvtpk(s[kvb][0], s[kvb][1]), y0 = cvtpk(s[kvb][4], s[kvb][5]);
            u32 x1 = cvtpk(s[kvb][2], s[kvb][3]), y1 = cvtpk(s[kvb][6], s[kvb][7]);
            u32 x2 = cvtpk(s[kvb][8], s[kvb][9]), y2 = cvtpk(s[kvb][12], s[kvb][13]);
            u32 x3 = cvtpk(s[kvb][10], s[kvb][11]), y3 = cvtpk(s[kvb][14], s[kvb][15]);
            plswap(x0, y0); plswap(x1, y1); plswap(x2, y2); plswap(x3, y3);
            u32x4v plo = {x0, x1, y0, y1};
            u32x4v phi = {x2, x3, y2, y3};
            pb[2 * kvb] = __builtin_bit_cast(bf16x8, plo);
            pb[2 * kvb + 1] = __builtin_bit_cast(bf16x8, phi);
        }

        // PV: O^T += V^T * P^T ; lsum via ones-row MFMA
        bf16x8 va[2][4];
#pragma unroll
        for (int db = 0; db < 2; db++)
#pragma unroll
            for (int ks = 0; ks < 4; ks++)
                va[db][ks] = *reinterpret_cast<const bf16x8*>(VL(g, c) + ks * 2048 + db * 1024 + fbase);
        __builtin_amdgcn_s_setprio(1);
#pragma unroll
        for (int ks = 0; ks < 4; ks++) {
            accO[0] = __builtin_amdgcn_mfma_f32_32x32x16_bf16(va[0][ks], pb[ks], accO[0], 0, 0, 0);
            accO[1] = __builtin_amdgcn_mfma_f32_32x32x16_bf16(va[1][ks], pb[ks], accO[1], 0, 0, 0);
            accL = __builtin_amdgcn_mfma_f32_32x32x16_bf16(ones, pb[ks], accL, 0, 0, 0);
        }
        __builtin_amdgcn_s_setprio(0);

        RAW_BAR();  // all waves done reading buf[c] before stage(pp+2) overwrites it
    }
#undef STAGE

    float lsum = accL[0];  // complete row-sum for this kv half

    // merge the two kv groups via LDS (exact: no max involved)
    float* mbuf = (float*)smem;
    int base = (wg * 64 + lane) * 36;  // 144B stride, 16B-aligned
    if (g == 1) {
#pragma unroll
        for (int db = 0; db < 2; db++)
#pragma unroll
            for (int q4 = 0; q4 < 4; q4++) {
                f32x4 v4 = {accO[db][q4 * 4 + 0], accO[db][q4 * 4 + 1],
                            accO[db][q4 * 4 + 2], accO[db][q4 * 4 + 3]};
                *reinterpret_cast<f32x4*>(mbuf + base + db * 16 + q4 * 4) = v4;
            }
        mbuf[base + 32] = lsum;
    }
    __syncthreads();
    if (g == 0) {
        float lsum2 = mbuf[base + 32];
        float inv = 1.f / (lsum + lsum2);
        int b = bh >> 4, h = bh & 15;
        u16* ob = o + ((size_t)(b * 2048 + q0 + l31)) * 1024 + h * 64;
#pragma unroll
        for (int db = 0; db < 2; db++) {
            f32x4 m4[4];
#pragma unroll
            for (int q4 = 0; q4 < 4; q4++)
                m4[q4] = *reinterpret_cast<const f32x4*>(mbuf + base + db * 16 + q4 * 4);
#pragma unroll
            for (int i = 0; i < 8; i++) {
                int r = 2 * i;
                int d = (r & 3) + 8 * (r >> 2) + 4 * hi + 32 * db;
                float lo = (accO[db][r] + m4[r >> 2][r & 3]) * inv;
                float hi_ = (accO[db][r + 1] + m4[(r + 1) >> 2][(r + 1) & 3]) * inv;
                *reinterpret_cast<u32*>(ob + d) = cvtpk(lo, hi_);
            }
        }
    }
#undef KL
#undef VL
}

// ---------------- launch ----------------

extern "C" void kernel_launch(void* const* d_in, const int* in_sizes, int n_in,
                              void* d_out, int out_size, void* d_ws, size_t ws_size,
                              hipStream_t stream) {
    (void)in_sizes; (void)n_in; (void)out_size; (void)ws_size;
    const float* x = (const float*)d_in[0];
    const float* w_qkv = (const float*)d_in[1];
    const float* w_proj = (const float*)d_in[2];
    const float* b_proj = (const float*)d_in[3];
    float* out = (float*)d_out;
    char* ws = (char*)d_ws;

    u16* xb   = (u16*)(ws + 0);            // 4096x1024 bf16
    u16* wqt  = (u16*)(ws + 8388608);      // 3072x1024 bf16
    u16* wpt  = (u16*)(ws + 14680064);     // 1024x1024 bf16
    u16* qws  = (u16*)(ws + 16777216);     // [32][2048][64] bf16 (pre-scaled by 0.125*log2e)
    u16* kws  = (u16*)(ws + 25165824);
    u16* vtws = (u16*)(ws + 41943040);     // [32][64][2048] bf16 (written transposed by GEMM1)
    u16* attn = (u16*)(ws + 50331648);     // [4096][1024] bf16

    prep_kernel<<<6144, 256, 0, stream>>>(x, xb, w_qkv, wqt, w_proj, wpt);
    gemm1_kernel<<<768, 256, 0, stream>>>(xb, wqt, qws, kws, vtws);
    flash6_kernel<<<dim3(16, 32), 512, 0, stream>>>(qws, kws, vtws, attn);
    gemm2_kernel<<<1024, 256, 0, stream>>>(attn, wpt, out, b_proj);
}